// Round 4
// baseline (742.170 us; speedup 1.0000x reference)
//
#include <hip/hip_runtime.h>
#include <math.h>

#define RMINF  0.5f
#define LSPAN  5.5f          // RC - RMIN
constexpr int BETA = 12, M1 = 24, M2 = 6;
constexpr int B_ = 4, N_ = 1024, NT_ = 2, MN_ = 128;
constexpr int K_ = NT_ * MN_;        // 256
constexpr int NFEAT = M1 * M2;       // 144
constexpr int HID = 128;
constexpr float PI_F = 3.14159265358979323846f;

// Output layout: Etot(4) | Ei(4096) | Force(4*1024*3) | Virial(36)
constexpr int EI_OFF = B_;                  // 4
constexpr int F_OFF  = B_ + B_ * N_;        // 4100
constexpr int V_OFF  = F_OFF + B_ * N_ * 3; // 16388

// Workspace layout (floats)
constexpr size_t WS_FEAT = 0;                          // 4096*144 (reused as dfeat)
constexpr size_t WS_R    = (size_t)B_ * N_ * NFEAT;    // 4096*96
constexpr size_t WS_VIR  = WS_R + (size_t)B_ * N_ * 96;// 4096*9

__global__ void zero_force_kernel(float* __restrict__ out) {
    int i = blockIdx.x * blockDim.x + threadIdx.x;
    if (i < B_ * N_ * 3) out[F_OFF + i] = 0.0f;
}

// ---------------- K1: embedding forward -> feat, R ----------------
__global__ __launch_bounds__(256, 4) void k1_embed(
    const int*   __restrict__ list_neigh,
    const int*   __restrict__ type_map,
    const float* __restrict__ imagedr,
    const float* __restrict__ c_param,
    const float* __restrict__ scale,
    float* __restrict__ feat_ws,
    float* __restrict__ R_ws)
{
    __shared__ float c_sh[NT_ * M1 * BETA];
    __shared__ float s_sh[K_ * 25];
    __shared__ float sr_sh[K_ * 5];
    __shared__ float Rpart[2 * 96];
    __shared__ float R_sh[96];

    const int tid = threadIdx.x;
    const int bn = blockIdx.x;
    const int n  = bn % N_;
    const int tn = type_map[n];

    for (int i = tid; i < NT_ * M1 * BETA; i += 256)
        c_sh[i] = c_param[tn * (NT_ * M1 * BETA) + i];

    const int k  = tid;
    const int tk = k >> 7;
    const int lni = list_neigh[(size_t)bn * K_ + k];
    const float valid = (lni >= 0) ? 1.0f : 0.0f;

    const float4 dr4 = reinterpret_cast<const float4*>(imagedr)[(size_t)bn * K_ + k];
    const float rx = dr4.y, ry = dr4.z, rz = dr4.w;
    const float r  = sqrtf(rx*rx + ry*ry + rz*rz + 1e-12f);
    const float uraw = (r - RMINF) / LSPAN;
    const float u  = fminf(fmaxf(uraw, 0.0f), 1.0f);
    const float fc = 0.5f * (cosf(PI_F * u) + 1.0f) * valid;
    const float x  = 2.0f * (r - RMINF) / LSPAN - 1.0f;

    float T[BETA];
    T[0] = 1.0f; T[1] = x;
#pragma unroll
    for (int j = 2; j < BETA; ++j) T[j] = 2.0f * x * T[j-1] - T[j-2];

    const float inv_r = 1.0f / r;
    sr_sh[k * 5 + 0] = valid;
    sr_sh[k * 5 + 1] = valid * rx * inv_r;
    sr_sh[k * 5 + 2] = valid * ry * inv_r;
    sr_sh[k * 5 + 3] = valid * rz * inv_r;

    __syncthreads();   // c_sh ready

    const float* crow = &c_sh[tk * M1 * BETA];
#pragma unroll
    for (int f = 0; f < M1; ++f) {
        float a0 = 0.0f, a1 = 0.0f;
#pragma unroll
        for (int j = 0; j < BETA; j += 2) {
            a0 = fmaf(T[j],   crow[f * BETA + j],   a0);
            a1 = fmaf(T[j+1], crow[f * BETA + j+1], a1);
        }
        s_sh[k * 25 + f] = fc * (a0 + a1);
    }
    __syncthreads();

    if (tid < 192) {
        const int half = tid / 96, tt = tid % 96;
        const int f = tt >> 2, c = tt & 3;
        const int k0 = half * 128;
        float a0 = 0.0f, a1 = 0.0f;
        for (int kk = k0; kk < k0 + 128; kk += 2) {
            a0 = fmaf(s_sh[kk * 25 + f],     sr_sh[kk * 5 + c],     a0);
            a1 = fmaf(s_sh[(kk+1) * 25 + f], sr_sh[(kk+1) * 5 + c], a1);
        }
        Rpart[half * 96 + tt] = a0 + a1;
    }
    __syncthreads();
    if (tid < 96) {
        const float v = (Rpart[tid] + Rpart[96 + tid]) * (1.0f / MN_);
        R_sh[tid] = v;
        R_ws[(size_t)bn * 96 + tid] = v;
    }
    __syncthreads();
    if (tid < NFEAT) {
        const int f = tid / 6, g = tid % 6;
        float acc = 0.0f;
#pragma unroll
        for (int c = 0; c < 4; ++c) acc += R_sh[f * 4 + c] * R_sh[g * 4 + c];
        feat_ws[(size_t)bn * NFEAT + tid] = acc * scale[tid];
    }
}

// ---------------- K2: MLP fwd + bwd (2 atoms per block) ----------------
__global__ __launch_bounds__(256, 4) void k2_mlp(
    const int*   __restrict__ type_map,
    const float* __restrict__ scale,
    const float* __restrict__ W0,
    const float* __restrict__ b0,
    const float* __restrict__ W1,
    const float* __restrict__ b1,
    const float* __restrict__ W2,
    const float* __restrict__ b2,
    const float* __restrict__ eshift,
    const float* __restrict__ feat_ws,
    float* __restrict__ dfeat_ws,     // may alias feat_ws
    float* __restrict__ out)
{
    __shared__ float feat_sh[2][NFEAT];
    __shared__ float h_sh[2][HID];
    __shared__ float dz1_sh[2][HID];
    __shared__ float dz0_sh[2][HID];
    __shared__ float red[4];

    const int tid = threadIdx.x;
    const int a   = tid >> 7;          // atom slot 0/1
    const int c   = tid & 127;         // column / row index
    const int lane = tid & 63;
    const int wid  = tid >> 6;
    const int bn = blockIdx.x * 2 + a;
    const int n  = bn % N_;
    const int tn = type_map[n];

    for (int i = tid; i < 2 * NFEAT; i += 256) {
        const int aa = i / NFEAT, f = i % NFEAT;
        feat_sh[aa][f] = feat_ws[(size_t)(blockIdx.x * 2 + aa) * NFEAT + f];
    }
    __syncthreads();

    // layer 0
    float acc0 = b0[tn * HID + c], acc0b = 0.0f;
    const float* w0c = W0 + (size_t)tn * NFEAT * HID + c;
#pragma unroll 8
    for (int f = 0; f < NFEAT; f += 2) {
        acc0  = fmaf(feat_sh[a][f],   w0c[f * HID],       acc0);
        acc0b = fmaf(feat_sh[a][f+1], w0c[(f+1) * HID],   acc0b);
    }
    const float h = tanhf(acc0 + acc0b);
    h_sh[a][c] = h;
    __syncthreads();

    // layer 1
    float acc1 = b1[tn * HID + c], acc1b = 0.0f;
    const float* w1c = W1 + (size_t)tn * HID * HID + c;
#pragma unroll 8
    for (int g = 0; g < HID; g += 2) {
        acc1  = fmaf(h_sh[a][g],   w1c[g * HID],       acc1);
        acc1b = fmaf(h_sh[a][g+1], w1c[(g+1) * HID],   acc1b);
    }
    const float t1 = tanhf(acc1 + acc1b);
    const float w2c = W2[tn * HID + c];
    const float dz1 = w2c * (1.0f - t1 * t1);
    dz1_sh[a][c] = dz1;

    // Ei = sum over c of (t1+h)*w2c
    {
        float v = (t1 + h) * w2c;
#pragma unroll
        for (int m = 32; m >= 1; m >>= 1) v += __shfl_xor(v, m);
        if (lane == 0) red[wid] = v;
    }
    __syncthreads();
    if (c == 0)
        out[EI_OFF + bn] = red[a * 2] + red[a * 2 + 1] + b2[tn] + eshift[tn];

    // dz0[h] = (W2[h] + sum_g W1[h][g]*dz1[g]) * (1-h^2)
    {
        const float4* w1row = reinterpret_cast<const float4*>(W1 + (size_t)(tn * HID + c) * HID);
        float ar = w2c, arb = 0.0f;
#pragma unroll 4
        for (int g4 = 0; g4 < HID / 4; g4 += 2) {
            const float4 w  = w1row[g4];
            const float4 w2 = w1row[g4 + 1];
            ar  += w.x  * dz1_sh[a][g4*4+0] + w.y  * dz1_sh[a][g4*4+1]
                 + w.z  * dz1_sh[a][g4*4+2] + w.w  * dz1_sh[a][g4*4+3];
            arb += w2.x * dz1_sh[a][g4*4+4] + w2.y * dz1_sh[a][g4*4+5]
                 + w2.z * dz1_sh[a][g4*4+6] + w2.w * dz1_sh[a][g4*4+7];
        }
        dz0_sh[a][c] = (ar + arb) * (1.0f - h * h);
    }
    __syncthreads();

    // dfeat[f] = scale[f] * sum_h W0[f][h] * dz0[h]
    for (int f = c; f < NFEAT; f += 128) {
        const float4* w0row = reinterpret_cast<const float4*>(W0 + (size_t)(tn * NFEAT + f) * HID);
        float ar = 0.0f, arb = 0.0f;
#pragma unroll 4
        for (int h4 = 0; h4 < HID / 4; h4 += 2) {
            const float4 w  = w0row[h4];
            const float4 w2 = w0row[h4 + 1];
            ar  += w.x  * dz0_sh[a][h4*4+0] + w.y  * dz0_sh[a][h4*4+1]
                 + w.z  * dz0_sh[a][h4*4+2] + w.w  * dz0_sh[a][h4*4+3];
            arb += w2.x * dz0_sh[a][h4*4+4] + w2.y * dz0_sh[a][h4*4+5]
                 + w2.z * dz0_sh[a][h4*4+6] + w2.w * dz0_sh[a][h4*4+7];
        }
        dfeat_ws[(size_t)bn * NFEAT + f] = (ar + arb) * scale[f];
    }
}

// ---------------- K3: embedding backward + force scatter ----------------
__global__ __launch_bounds__(256, 4) void k3_bwd(
    const int*   __restrict__ list_neigh,
    const int*   __restrict__ type_map,
    const float* __restrict__ imagedr,
    const float* __restrict__ c_param,
    const float* __restrict__ dfeat_ws,
    const float* __restrict__ R_ws,
    float* __restrict__ out,
    float* __restrict__ vir_ws)
{
    __shared__ float c_sh[NT_ * M1 * BETA];
    __shared__ float dfeat_sh[NFEAT];
    __shared__ float R_sh[96];
    __shared__ float dR_sh[96];
    __shared__ float red12[12 * 4];

    const int tid  = threadIdx.x;
    const int lane = tid & 63;
    const int wid  = tid >> 6;
    const int bn = blockIdx.x;
    const int b  = bn / N_;
    const int n  = bn % N_;
    const int tn = type_map[n];

    for (int i = tid; i < NT_ * M1 * BETA; i += 256)
        c_sh[i] = c_param[tn * (NT_ * M1 * BETA) + i];
    if (tid < NFEAT) dfeat_sh[tid] = dfeat_ws[(size_t)bn * NFEAT + tid];
    if (tid < 96)    R_sh[tid]     = R_ws[(size_t)bn * 96 + tid];

    const int k  = tid;
    const int tk = k >> 7;
    const int lni = list_neigh[(size_t)bn * K_ + k];
    const float valid = (lni >= 0) ? 1.0f : 0.0f;

    const float4 dr4 = reinterpret_cast<const float4*>(imagedr)[(size_t)bn * K_ + k];
    const float rx = dr4.y, ry = dr4.z, rz = dr4.w;
    const float r  = sqrtf(rx*rx + ry*ry + rz*rz + 1e-12f);
    const float uraw = (r - RMINF) / LSPAN;
    const float u  = fminf(fmaxf(uraw, 0.0f), 1.0f);
    const float fc = 0.5f * (cosf(PI_F * u) + 1.0f) * valid;
    const float x  = 2.0f * (r - RMINF) / LSPAN - 1.0f;

    float T[BETA];
    T[0] = 1.0f; T[1] = x;
#pragma unroll
    for (int j = 2; j < BETA; ++j) T[j] = 2.0f * x * T[j-1] - T[j-2];

    const float inv_r = 1.0f / r;
    const float sr0 = valid;
    const float sr1 = valid * rx * inv_r;
    const float sr2 = valid * ry * inv_r;
    const float sr3 = valid * rz * inv_r;

    __syncthreads();   // shared loads done

    if (tid < 96) {
        const int p = tid >> 2, c = tid & 3;
        float acc = 0.0f;
#pragma unroll
        for (int g = 0; g < M2; ++g) acc += dfeat_sh[p * 6 + g] * R_sh[g * 4 + c];
        if (p < M2) {
            for (int f = 0; f < M1; ++f) acc += dfeat_sh[f * 6 + p] * R_sh[f * 4 + c];
        }
        dR_sh[p * 4 + c] = acc * (1.0f / MN_);
    }
    __syncthreads();

    const float* crow = &c_sh[tk * M1 * BETA];
    float cj[BETA];
#pragma unroll
    for (int j = 0; j < BETA; ++j) cj[j] = 0.0f;
    float dsr1 = 0.0f, dsr2 = 0.0f, dsr3 = 0.0f, dfc = 0.0f;
#pragma unroll
    for (int f = 0; f < M1; ++f) {
        float sa = 0.0f, sb = 0.0f;
#pragma unroll
        for (int j = 0; j < BETA; j += 2) {
            sa = fmaf(T[j],   crow[f * BETA + j],   sa);
            sb = fmaf(T[j+1], crow[f * BETA + j+1], sb);
        }
        const float sf = sa + sb;
        const float d0 = dR_sh[f*4+0], d1 = dR_sh[f*4+1], d2 = dR_sh[f*4+2], d3 = dR_sh[f*4+3];
        const float dsf = d0 * sr0 + d1 * sr1 + d2 * sr2 + d3 * sr3;
        dfc += dsf * sf;
        const float dsg = dsf * fc;
#pragma unroll
        for (int j = 0; j < BETA; ++j) cj[j] = fmaf(dsg, crow[f * BETA + j], cj[j]);
        const float sk = fc * sf;
        dsr1 = fmaf(d1, sk, dsr1); dsr2 = fmaf(d2, sk, dsr2); dsr3 = fmaf(d3, sk, dsr3);
    }
    float dx = cj[1];
    float tpm1 = 1.0f, tpm2 = 0.0f;
#pragma unroll
    for (int j = 2; j < BETA; ++j) {
        const float tp = 2.0f * T[j-1] + 2.0f * x * tpm1 - tpm2;
        dx = fmaf(cj[j], tp, dx);
        tpm2 = tpm1; tpm1 = tp;
    }
    float dfcdr = 0.0f;
    if (uraw > 0.0f && uraw < 1.0f)
        dfcdr = -0.5f * PI_F * sinf(PI_F * u) * valid / LSPAN;
    const float drt = dx * (2.0f / LSPAN) + dfc * dfcdr;
    const float Sdot = dsr1 * rx + dsr2 * ry + dsr3 * rz;
    const float common = drt * inv_r - valid * Sdot * inv_r * inv_r * inv_r;
    const float gx = common * rx + valid * dsr1 * inv_r;
    const float gy = common * ry + valid * dsr2 * inv_r;
    const float gz = common * rz + valid * dsr3 * inv_r;

    if (lni >= 0) {
        float* fp = out + F_OFF + ((size_t)b * N_ + lni) * 3;
        atomicAdd(fp + 0, -gx);
        atomicAdd(fp + 1, -gy);
        atomicAdd(fp + 2, -gz);
    }

    float vals[12];
    vals[0] = gx; vals[1] = gy; vals[2] = gz;
    vals[3] = -rx * gx; vals[4]  = -rx * gy; vals[5]  = -rx * gz;
    vals[6] = -ry * gx; vals[7]  = -ry * gy; vals[8]  = -ry * gz;
    vals[9] = -rz * gx; vals[10] = -rz * gy; vals[11] = -rz * gz;
#pragma unroll
    for (int i = 0; i < 12; ++i) {
        float v = vals[i];
#pragma unroll
        for (int m = 32; m >= 1; m >>= 1) v += __shfl_xor(v, m);
        if (lane == 0) red12[i * 4 + wid] = v;
    }
    __syncthreads();
    if (tid < 12) {
        const float v = red12[tid*4+0] + red12[tid*4+1] + red12[tid*4+2] + red12[tid*4+3];
        if (tid < 3) atomicAdd(&out[F_OFF + ((size_t)b * N_ + n) * 3 + tid], v);
        else         vir_ws[(size_t)bn * 9 + (tid - 3)] = v;
    }
}

// ---------------- K4: finalize Etot + Virial ----------------
__global__ __launch_bounds__(256) void k4_final(
    const float* __restrict__ vir_ws,
    float* __restrict__ out)
{
    __shared__ float red[10 * 4];
    const int tid  = threadIdx.x;
    const int lane = tid & 63;
    const int wid  = tid >> 6;
    const int b = blockIdx.x;

    float vals[10];
#pragma unroll
    for (int i = 0; i < 10; ++i) vals[i] = 0.0f;
    for (int n = tid; n < N_; n += 256) {
        vals[0] += out[EI_OFF + b * N_ + n];
        const float* vp = vir_ws + ((size_t)b * N_ + n) * 9;
#pragma unroll
        for (int j = 0; j < 9; ++j) vals[1 + j] += vp[j];
    }
#pragma unroll
    for (int i = 0; i < 10; ++i) {
        float v = vals[i];
#pragma unroll
        for (int m = 32; m >= 1; m >>= 1) v += __shfl_xor(v, m);
        if (lane == 0) red[i * 4 + wid] = v;
    }
    __syncthreads();
    if (tid < 10) {
        const float v = red[tid*4+0] + red[tid*4+1] + red[tid*4+2] + red[tid*4+3];
        if (tid == 0) out[b] = v;
        else          out[V_OFF + b * 9 + (tid - 1)] = v;
    }
}

extern "C" void kernel_launch(void* const* d_in, const int* in_sizes, int n_in,
                              void* d_out, int out_size, void* d_ws, size_t ws_size,
                              hipStream_t stream) {
    float* out = (float*)d_out;
    float* ws  = (float*)d_ws;
    float* feat_ws = ws + WS_FEAT;
    float* R_ws    = ws + WS_R;
    float* vir_ws  = ws + WS_VIR;

    const int*   list_neigh = (const int*)d_in[0];
    const int*   type_map   = (const int*)d_in[1];
    const float* imagedr    = (const float*)d_in[3];
    const float* c_param    = (const float*)d_in[6];
    const float* scale      = (const float*)d_in[7];
    const float* W0 = (const float*)d_in[8];
    const float* b0 = (const float*)d_in[9];
    const float* W1 = (const float*)d_in[10];
    const float* b1 = (const float*)d_in[11];
    const float* W2 = (const float*)d_in[12];
    const float* b2 = (const float*)d_in[13];
    const float* eshift = (const float*)d_in[14];

    zero_force_kernel<<<(B_ * N_ * 3 + 255) / 256, 256, 0, stream>>>(out);
    k1_embed<<<B_ * N_, 256, 0, stream>>>(list_neigh, type_map, imagedr, c_param,
                                          scale, feat_ws, R_ws);
    k2_mlp<<<B_ * N_ / 2, 256, 0, stream>>>(type_map, scale, W0, b0, W1, b1, W2, b2,
                                            eshift, feat_ws, feat_ws /*alias dfeat*/, out);
    k3_bwd<<<B_ * N_, 256, 0, stream>>>(list_neigh, type_map, imagedr, c_param,
                                        feat_ws /*dfeat*/, R_ws, out, vir_ws);
    k4_final<<<B_, 256, 0, stream>>>(vir_ws, out);
}